// Round 1
// baseline (1998.785 us; speedup 1.0000x reference)
//
#include <hip/hip_runtime.h>
#include <math.h>

namespace {
constexpr int BB   = 16;    // batch
constexpr int SS   = 32;    // grid side
constexpr int TT   = 256;   // tiles
constexpr int PP   = 1024;  // patches
constexpr int NTOK = 1025;  // N = R + P
constexpr int KCC  = 256;   // KC
constexpr int KTOK = 257;   // K = R + KC
constexpr int DD   = 768;
constexpr int HH   = 12;
constexpr int DHH  = 64;
}

// ---------------------------------------------------------------------------
// 1. tile-context pooling: ctx[b,0,:] = x[b,0,:]; ctx[b,1+t,:] = softmax-weighted
//    average of the 4 patch rows of tile t (weights = patch . logit_w).
// ---------------------------------------------------------------------------
__global__ __launch_bounds__(256) void ctx_kernel(
    const float* __restrict__ x, const float* __restrict__ logit_w,
    float* __restrict__ ctx) {
  const int blk = blockIdx.x;
  const int b = blk >> 8;    // / TT
  const int t = blk & 255;   // % TT
  const int tid = threadIdx.x;
  const float* xb = x + (size_t)b * NTOK * DD;

  int prow[4];
#pragma unroll
  for (int s = 0; s < 4; ++s)
    prow[s] = 1 + ((t >> 4) * 2 + (s >> 1)) * SS + ((t & 15) * 2 + (s & 1));

  float part[4] = {0.f, 0.f, 0.f, 0.f};
  for (int d = tid; d < DD; d += 256) {
    const float lw = logit_w[d];
#pragma unroll
    for (int s = 0; s < 4; ++s) part[s] += xb[(size_t)prow[s] * DD + d] * lw;
  }

  __shared__ float red[256];
  float score[4];
#pragma unroll
  for (int s = 0; s < 4; ++s) {
    red[tid] = part[s];
    __syncthreads();
    for (int off = 128; off > 0; off >>= 1) {
      if (tid < off) red[tid] += red[tid + off];
      __syncthreads();
    }
    score[s] = red[0];
    __syncthreads();
  }

  const float mx = fmaxf(fmaxf(score[0], score[1]), fmaxf(score[2], score[3]));
  float e[4], sum = 0.f;
#pragma unroll
  for (int s = 0; s < 4; ++s) { e[s] = expf(score[s] - mx); sum += e[s]; }
  const float inv = 1.f / sum;

  float* crow = ctx + ((size_t)b * KTOK + 1 + t) * DD;
  for (int d = tid; d < DD; d += 256) {
    float acc = 0.f;
#pragma unroll
    for (int s = 0; s < 4; ++s) acc += (e[s] * inv) * xb[(size_t)prow[s] * DD + d];
    crow[d] = acc;
  }
  if (t == 0) {  // copy the register token row
    float* dst = ctx + (size_t)b * KTOK * DD;
    for (int d = tid; d < DD; d += 256) dst[d] = xb[d];
  }
}

// ---------------------------------------------------------------------------
// 2. fp32 NT GEMM: C[m,n] = sum_k A[m,k] * W[n,k] (+ bias[n]).
//    128x128 tile, BK=16, 256 threads, 8x8 microtile.
// ---------------------------------------------------------------------------
__global__ __launch_bounds__(256) void gemm_nt_kernel(
    const float* __restrict__ A, const float* __restrict__ W,
    const float* __restrict__ bias, float* __restrict__ C,
    int M, int Nout, int Kdim) {
  constexpr int BM = 128, BN = 128, BK = 16;
  __shared__ float As[BK][BM + 1];
  __shared__ float Ws[BK][BN + 1];
  const int tid = threadIdx.x;
  const int tx = tid & 15;
  const int ty = tid >> 4;
  const int row0 = blockIdx.y * BM;
  const int col0 = blockIdx.x * BN;
  const int lk = tid & 15;   // k lane for loading
  const int lm = tid >> 4;   // base row/col for loading

  float acc[8][8];
#pragma unroll
  for (int i = 0; i < 8; ++i)
#pragma unroll
    for (int j = 0; j < 8; ++j) acc[i][j] = 0.f;

  for (int k0 = 0; k0 < Kdim; k0 += BK) {
#pragma unroll
    for (int i = 0; i < 8; ++i) {
      const int m = lm + 16 * i;
      const int gr = row0 + m;
      As[lk][m] = (gr < M) ? A[(size_t)gr * Kdim + k0 + lk] : 0.f;
    }
#pragma unroll
    for (int j = 0; j < 8; ++j) {
      const int nn = lm + 16 * j;  // Nout is a multiple of 128: no guard
      Ws[lk][nn] = W[(size_t)(col0 + nn) * Kdim + k0 + lk];
    }
    __syncthreads();
#pragma unroll
    for (int kk = 0; kk < BK; ++kk) {
      float a[8], w[8];
#pragma unroll
      for (int i = 0; i < 8; ++i) a[i] = As[kk][ty + 16 * i];
#pragma unroll
      for (int j = 0; j < 8; ++j) w[j] = Ws[kk][tx + 16 * j];
#pragma unroll
      for (int i = 0; i < 8; ++i)
#pragma unroll
        for (int j = 0; j < 8; ++j) acc[i][j] += a[i] * w[j];
    }
    __syncthreads();
  }

#pragma unroll
  for (int i = 0; i < 8; ++i) {
    const int gr = row0 + ty + 16 * i;
    if (gr >= M) continue;
    float* crow = C + (size_t)gr * Nout;
#pragma unroll
    for (int j = 0; j < 8; ++j) {
      const int gc = col0 + tx + 16 * j;
      float v = acc[i][j];
      if (bias) v += bias[gc];
      crow[gc] = v;
    }
  }
}

// ---------------------------------------------------------------------------
// 3. CPB bias MLP -> biasT[h][c][p]  (layout (H, KC, P) for coalesced attn reads)
// ---------------------------------------------------------------------------
__global__ __launch_bounds__(256) void cpb_kernel(
    const float* __restrict__ P_pos, const float* __restrict__ tile_centers,
    const float* __restrict__ u_pos,
    const float* __restrict__ w1, const float* __restrict__ b1,
    const float* __restrict__ w2, const float* __restrict__ b2,
    float* __restrict__ biasT) {
  const int idx = blockIdx.x * 256 + threadIdx.x;  // c*1024 + p
  const int c = idx >> 10;
  const int p = idx & 1023;

  const float px = P_pos[p * 3 + 0], py = P_pos[p * 3 + 1], pz = P_pos[p * 3 + 2];
  const float kx = tile_centers[c * 3 + 0] + u_pos[0];
  const float ky = tile_centers[c * 3 + 1] + u_pos[1];
  const float kz = tile_centers[c * 3 + 2] + u_pos[2];
  const float dx = px - kx, dy = py - ky, dz = pz - kz;
  const float fx = copysignf(log1pf(fabsf(dx)), dx);
  const float fy = copysignf(log1pf(fabsf(dy)), dy);
  const float fz = -dz;

  float outh[HH];
#pragma unroll
  for (int h = 0; h < HH; ++h) outh[h] = b2[h];
  for (int j = 0; j < 32; ++j) {
    float hj = fx * w1[j * 3 + 0] + fy * w1[j * 3 + 1] + fz * w1[j * 3 + 2] + b1[j];
    hj = 0.5f * hj * (1.f + erff(hj * 0.70710678118654752f));  // exact gelu
#pragma unroll
    for (int h = 0; h < HH; ++h) outh[h] += hj * w2[h * 32 + j];
  }
#pragma unroll
  for (int h = 0; h < HH; ++h) biasT[((size_t)h * KCC + c) * PP + p] = outh[h];
}

// ---------------------------------------------------------------------------
// 4. attention: one thread per (b,h,n) query row. Online softmax over K=257.
//    q: (B,N,D) with head segment h*64; kv: (B,K,1536) k at +0, v at +768.
//    o written to (B,N,D) so the output GEMM consumes it directly.
// ---------------------------------------------------------------------------
__global__ __launch_bounds__(64) void attn_kernel(
    const float* __restrict__ q, const float* __restrict__ kv,
    const float* __restrict__ biasT, float* __restrict__ o) {
  const int n = blockIdx.x * 64 + threadIdx.x;
  const int h = blockIdx.y;
  const int b = blockIdx.z;
  if (n >= NTOK) return;

  float qr[DHH];
  const float4* q4 = reinterpret_cast<const float4*>(q + ((size_t)(b * NTOK + n) * DD) + h * DHH);
#pragma unroll
  for (int i = 0; i < 16; ++i) {
    const float4 v = q4[i];
    qr[4 * i + 0] = v.x * 0.125f;  // fold scale = DH^-0.5
    qr[4 * i + 1] = v.y * 0.125f;
    qr[4 * i + 2] = v.z * 0.125f;
    qr[4 * i + 3] = v.w * 0.125f;
  }

  const float* kvb = kv + (size_t)b * KTOK * (2 * DD) + h * DHH;
  const float* brow = biasT + (size_t)h * KCC * PP + (n - 1);  // valid only n>=1

  float m = -3.0e38f, l = 0.f;
  float acc[DHH];
#pragma unroll
  for (int i = 0; i < DHH; ++i) acc[i] = 0.f;

  for (int kk = 0; kk < KTOK; ++kk) {
    const float4* k4 = reinterpret_cast<const float4*>(kvb + (size_t)kk * 2 * DD);
    float s = 0.f;
#pragma unroll
    for (int i = 0; i < 16; ++i) {
      const float4 kw = k4[i];
      s += qr[4 * i + 0] * kw.x + qr[4 * i + 1] * kw.y +
           qr[4 * i + 2] * kw.z + qr[4 * i + 3] * kw.w;
    }
    if (n >= 1 && kk >= 1) s += brow[(size_t)(kk - 1) * PP];

    const float4* v4 = reinterpret_cast<const float4*>(kvb + (size_t)kk * 2 * DD + DD);
    if (s <= m) {
      const float p = expf(s - m);
      l += p;
#pragma unroll
      for (int i = 0; i < 16; ++i) {
        const float4 vw = v4[i];
        acc[4 * i + 0] += p * vw.x;
        acc[4 * i + 1] += p * vw.y;
        acc[4 * i + 2] += p * vw.z;
        acc[4 * i + 3] += p * vw.w;
      }
    } else {
      const float corr = expf(m - s);
      l = l * corr + 1.f;
#pragma unroll
      for (int i = 0; i < 16; ++i) {
        const float4 vw = v4[i];
        acc[4 * i + 0] = acc[4 * i + 0] * corr + vw.x;
        acc[4 * i + 1] = acc[4 * i + 1] * corr + vw.y;
        acc[4 * i + 2] = acc[4 * i + 2] * corr + vw.z;
        acc[4 * i + 3] = acc[4 * i + 3] * corr + vw.w;
      }
      m = s;
    }
  }

  const float inv = 1.f / l;
  float4* o4 = reinterpret_cast<float4*>(o + ((size_t)(b * NTOK + n) * DD) + h * DHH);
#pragma unroll
  for (int i = 0; i < 16; ++i) {
    o4[i] = make_float4(acc[4 * i + 0] * inv, acc[4 * i + 1] * inv,
                        acc[4 * i + 2] * inv, acc[4 * i + 3] * inv);
  }
}

// ---------------------------------------------------------------------------
extern "C" void kernel_launch(void* const* d_in, const int* in_sizes, int n_in,
                              void* d_out, int out_size, void* d_ws, size_t ws_size,
                              hipStream_t stream) {
  const float* x            = (const float*)d_in[0];
  const float* logit_w      = (const float*)d_in[1];
  const float* q_w          = (const float*)d_in[2];
  const float* kv_w         = (const float*)d_in[3];
  const float* out_w        = (const float*)d_in[4];
  const float* out_b        = (const float*)d_in[5];
  const float* cpb_w1       = (const float*)d_in[6];
  const float* cpb_b1       = (const float*)d_in[7];
  const float* cpb_w2       = (const float*)d_in[8];
  const float* cpb_b2       = (const float*)d_in[9];
  const float* u_pos        = (const float*)d_in[10];
  const float* P_pos        = (const float*)d_in[11];
  const float* tile_centers = (const float*)d_in[12];
  float* out = (float*)d_out;

  float* ws    = (float*)d_ws;
  float* ctx   = ws;                                  // B*K*D      = 3,158,016 f
  float* qbuf  = ctx   + (size_t)BB * KTOK * DD;      // B*N*D      = 12,595,200 f
  float* kvbuf = qbuf  + (size_t)BB * NTOK * DD;      // B*K*2D     = 6,316,032 f
  float* biasT = kvbuf + (size_t)BB * KTOK * 2 * DD;  // H*KC*P     = 3,145,728 f
  float* obuf  = biasT + (size_t)HH * KCC * PP;       // B*N*D      = 12,595,200 f
  // total ~151.2 MB of d_ws

  const int Mq = BB * NTOK;   // 16400
  const int Mkv = BB * KTOK;  // 4112

  ctx_kernel<<<BB * TT, 256, 0, stream>>>(x, logit_w, ctx);
  gemm_nt_kernel<<<dim3(DD / 128, (Mq + 127) / 128), 256, 0, stream>>>(
      x, q_w, nullptr, qbuf, Mq, DD, DD);
  gemm_nt_kernel<<<dim3(2 * DD / 128, (Mkv + 127) / 128), 256, 0, stream>>>(
      ctx, kv_w, nullptr, kvbuf, Mkv, 2 * DD, DD);
  cpb_kernel<<<(PP * KCC) / 256, 256, 0, stream>>>(
      P_pos, tile_centers, u_pos, cpb_w1, cpb_b1, cpb_w2, cpb_b2, biasT);
  attn_kernel<<<dim3((NTOK + 63) / 64, HH, BB), 64, 0, stream>>>(
      qbuf, kvbuf, biasT, obuf);
  gemm_nt_kernel<<<dim3(DD / 128, (Mq + 127) / 128), 256, 0, stream>>>(
      obuf, out_w, out_b, out, Mq, DD, DD);
}

// Round 2
// 836.043 us; speedup vs baseline: 2.3908x; 2.3908x over previous
//
#include <hip/hip_runtime.h>
#include <math.h>

namespace {
constexpr int BB   = 16;    // batch
constexpr int SS   = 32;    // grid side
constexpr int TT   = 256;   // tiles
constexpr int PP   = 1024;  // patches
constexpr int NTOK = 1025;  // N = R + P
constexpr int KCC  = 256;   // KC
constexpr int KTOK = 257;   // K = R + KC
constexpr int DD   = 768;
constexpr int HH   = 12;
constexpr int DHH  = 64;
}

typedef _Float16 f16x8 __attribute__((ext_vector_type(8)));
typedef float f32x4 __attribute__((ext_vector_type(4)));

// ---------------------------------------------------------------------------
// 1. tile-context pooling (unchanged from round 1)
// ---------------------------------------------------------------------------
__global__ __launch_bounds__(256) void ctx_kernel(
    const float* __restrict__ x, const float* __restrict__ logit_w,
    float* __restrict__ ctx) {
  const int blk = blockIdx.x;
  const int b = blk >> 8;
  const int t = blk & 255;
  const int tid = threadIdx.x;
  const float* xb = x + (size_t)b * NTOK * DD;

  int prow[4];
#pragma unroll
  for (int s = 0; s < 4; ++s)
    prow[s] = 1 + ((t >> 4) * 2 + (s >> 1)) * SS + ((t & 15) * 2 + (s & 1));

  float part[4] = {0.f, 0.f, 0.f, 0.f};
  for (int d = tid; d < DD; d += 256) {
    const float lw = logit_w[d];
#pragma unroll
    for (int s = 0; s < 4; ++s) part[s] += xb[(size_t)prow[s] * DD + d] * lw;
  }

  __shared__ float red[256];
  float score[4];
#pragma unroll
  for (int s = 0; s < 4; ++s) {
    red[tid] = part[s];
    __syncthreads();
    for (int off = 128; off > 0; off >>= 1) {
      if (tid < off) red[tid] += red[tid + off];
      __syncthreads();
    }
    score[s] = red[0];
    __syncthreads();
  }

  const float mx = fmaxf(fmaxf(score[0], score[1]), fmaxf(score[2], score[3]));
  float e[4], sum = 0.f;
#pragma unroll
  for (int s = 0; s < 4; ++s) { e[s] = expf(score[s] - mx); sum += e[s]; }
  const float inv = 1.f / sum;

  float* crow = ctx + ((size_t)b * KTOK + 1 + t) * DD;
  for (int d = tid; d < DD; d += 256) {
    float acc = 0.f;
#pragma unroll
    for (int s = 0; s < 4; ++s) acc += (e[s] * inv) * xb[(size_t)prow[s] * DD + d];
    crow[d] = acc;
  }
  if (t == 0) {
    float* dst = ctx + (size_t)b * KTOK * DD;
    for (int d = tid; d < DD; d += 256) dst[d] = xb[d];
  }
}

// ---------------------------------------------------------------------------
// 2. fp16-split MFMA NT GEMM: C[m,n] = sum_k A[m,k]*W[n,k] (+bias), K=768.
//    a = a_hi + a_lo (fp16 each); acc += hi*hi + hi*lo + lo*hi  (~fp32 acc).
//    128x128 tile, BK=32, 256 thr = 4 waves (2x2), 64x64 per wave,
//    mfma_f32_16x16x32_f16: A row=lane&15, k=(lane>>4)*8+j;
//    C/D col=lane&15, row=(lane>>4)*4+reg.
// ---------------------------------------------------------------------------
__global__ __launch_bounds__(256) void gemm_nt_f16split_kernel(
    const float* __restrict__ A, const float* __restrict__ W,
    const float* __restrict__ bias, float* __restrict__ C,
    int M, int Nout) {
  constexpr int BK = 32;
  constexpr int LDT = BK + 8;  // 40 halves = 80 B row stride (16B-aligned)
  alignas(16) __shared__ _Float16 Ah[128][LDT];
  alignas(16) __shared__ _Float16 Al[128][LDT];
  alignas(16) __shared__ _Float16 Wh[128][LDT];
  alignas(16) __shared__ _Float16 Wl[128][LDT];

  const int tid = threadIdx.x;
  const int lane = tid & 63;
  const int wid = tid >> 6;
  const int awm = (wid >> 1) * 64;
  const int awn = (wid & 1) * 64;
  const int fr = lane & 15;
  const int kb = (lane >> 4) * 8;

  const int row0 = blockIdx.y * 128;
  const int col0 = blockIdx.x * 128;

  const int sr = tid >> 3;        // 0..31 staging row
  const int sc = (tid & 7) * 4;   // float col within BK

  const f32x4 zero = {0.f, 0.f, 0.f, 0.f};
  f32x4 acc[4][4];
#pragma unroll
  for (int i = 0; i < 4; ++i)
#pragma unroll
    for (int j = 0; j < 4; ++j) acc[i][j] = zero;

  for (int k0 = 0; k0 < DD; k0 += BK) {
    __syncthreads();
#pragma unroll
    for (int rr = 0; rr < 4; ++rr) {
      const int m = sr + 32 * rr;
      const int gr = row0 + m;
      float4 v = make_float4(0.f, 0.f, 0.f, 0.f);
      if (gr < M) v = *(const float4*)&A[(size_t)gr * DD + k0 + sc];
      float va[4] = {v.x, v.y, v.z, v.w};
#pragma unroll
      for (int e = 0; e < 4; ++e) {
        const _Float16 hi = (_Float16)va[e];
        Ah[m][sc + e] = hi;
        Al[m][sc + e] = (_Float16)(va[e] - (float)hi);
      }
      const float4 wv = *(const float4*)&W[(size_t)(col0 + m) * DD + k0 + sc];
      float wa[4] = {wv.x, wv.y, wv.z, wv.w};
#pragma unroll
      for (int e = 0; e < 4; ++e) {
        const _Float16 hi = (_Float16)wa[e];
        Wh[m][sc + e] = hi;
        Wl[m][sc + e] = (_Float16)(wa[e] - (float)hi);
      }
    }
    __syncthreads();

    f16x8 ah[4], al[4], bh[4], bl[4];
#pragma unroll
    for (int i = 0; i < 4; ++i) {
      ah[i] = *(const f16x8*)&Ah[awm + i * 16 + fr][kb];
      al[i] = *(const f16x8*)&Al[awm + i * 16 + fr][kb];
      bh[i] = *(const f16x8*)&Wh[awn + i * 16 + fr][kb];
      bl[i] = *(const f16x8*)&Wl[awn + i * 16 + fr][kb];
    }
#pragma unroll
    for (int i = 0; i < 4; ++i)
#pragma unroll
      for (int j = 0; j < 4; ++j) {
        acc[i][j] = __builtin_amdgcn_mfma_f32_16x16x32_f16(ah[i], bh[j], acc[i][j], 0, 0, 0);
        acc[i][j] = __builtin_amdgcn_mfma_f32_16x16x32_f16(ah[i], bl[j], acc[i][j], 0, 0, 0);
        acc[i][j] = __builtin_amdgcn_mfma_f32_16x16x32_f16(al[i], bh[j], acc[i][j], 0, 0, 0);
      }
  }

#pragma unroll
  for (int i = 0; i < 4; ++i) {
    const int rbase = row0 + awm + i * 16 + ((lane >> 4) << 2);
#pragma unroll
    for (int reg = 0; reg < 4; ++reg) {
      const int gr = rbase + reg;
      if (gr >= M) continue;
      float* crow = C + (size_t)gr * Nout + col0;
#pragma unroll
      for (int j = 0; j < 4; ++j) {
        const int gc = awn + j * 16 + fr;
        float v = acc[i][j][reg];
        if (bias) v += bias[col0 + gc];
        crow[gc] = v;
      }
    }
  }
}

// ---------------------------------------------------------------------------
// 3. CPB bias MLP -> biasT[h][c][p]  (unchanged)
// ---------------------------------------------------------------------------
__global__ __launch_bounds__(256) void cpb_kernel(
    const float* __restrict__ P_pos, const float* __restrict__ tile_centers,
    const float* __restrict__ u_pos,
    const float* __restrict__ w1, const float* __restrict__ b1,
    const float* __restrict__ w2, const float* __restrict__ b2,
    float* __restrict__ biasT) {
  const int idx = blockIdx.x * 256 + threadIdx.x;
  const int c = idx >> 10;
  const int p = idx & 1023;

  const float px = P_pos[p * 3 + 0], py = P_pos[p * 3 + 1], pz = P_pos[p * 3 + 2];
  const float kx = tile_centers[c * 3 + 0] + u_pos[0];
  const float ky = tile_centers[c * 3 + 1] + u_pos[1];
  const float kz = tile_centers[c * 3 + 2] + u_pos[2];
  const float dx = px - kx, dy = py - ky, dz = pz - kz;
  const float fx = copysignf(log1pf(fabsf(dx)), dx);
  const float fy = copysignf(log1pf(fabsf(dy)), dy);
  const float fz = -dz;

  float outh[HH];
#pragma unroll
  for (int h = 0; h < HH; ++h) outh[h] = b2[h];
  for (int j = 0; j < 32; ++j) {
    float hj = fx * w1[j * 3 + 0] + fy * w1[j * 3 + 1] + fz * w1[j * 3 + 2] + b1[j];
    hj = 0.5f * hj * (1.f + erff(hj * 0.70710678118654752f));
#pragma unroll
    for (int h = 0; h < HH; ++h) outh[h] += hj * w2[h * 32 + j];
  }
#pragma unroll
  for (int h = 0; h < HH; ++h) biasT[((size_t)h * KCC + c) * PP + p] = outh[h];
}

// ---------------------------------------------------------------------------
// 4. attention: 256 threads/block, one thread per query, K/V chunks in LDS.
//    grid (5, 12, 16). Online softmax over K=257.
// ---------------------------------------------------------------------------
__global__ __launch_bounds__(256) void attn_kernel(
    const float* __restrict__ q, const float* __restrict__ kv,
    const float* __restrict__ biasT, float* __restrict__ o) {
  alignas(16) __shared__ float Ks[32][64];
  alignas(16) __shared__ float Vs[32][64];

  const int tid = threadIdx.x;
  const int n = blockIdx.x * 256 + tid;
  const int h = blockIdx.y;
  const int b = blockIdx.z;
  const bool valid = n < NTOK;

  f32x4 qr[16];
  if (valid) {
    const f32x4* q4 = (const f32x4*)(q + ((size_t)(b * NTOK + n) * DD) + h * DHH);
#pragma unroll
    for (int i = 0; i < 16; ++i) qr[i] = q4[i] * 0.125f;  // fold DH^-0.5
  } else {
#pragma unroll
    for (int i = 0; i < 16; ++i) qr[i] = (f32x4){0.f, 0.f, 0.f, 0.f};
  }

  const float* kvb = kv + (size_t)b * KTOK * (2 * DD) + h * DHH;
  const bool useb = valid && (n >= 1);
  const float* bcol = biasT + (size_t)h * KCC * PP + (n - 1);

  float m = -3.0e38f, l = 0.f;
  f32x4 acc[16];
#pragma unroll
  for (int i = 0; i < 16; ++i) acc[i] = (f32x4){0.f, 0.f, 0.f, 0.f};

  for (int k0 = 0; k0 < KTOK; k0 += 32) {
    const int kcnt = min(32, KTOK - k0);
    __syncthreads();
#pragma unroll
    for (int f = tid; f < 512; f += 256) {  // 32 rows x 16 float4
      const int kr = f >> 4;
      const int c4 = f & 15;
      if (kr < kcnt) {
        const float* row = kvb + (size_t)(k0 + kr) * (2 * DD);
        ((float4*)&Ks[kr][0])[c4] = ((const float4*)row)[c4];
        ((float4*)&Vs[kr][0])[c4] = ((const float4*)(row + DD))[c4];
      }
    }
    __syncthreads();

    for (int kk = 0; kk < kcnt; ++kk) {
      const f32x4* krow = (const f32x4*)Ks[kk];
      f32x4 sv = (f32x4){0.f, 0.f, 0.f, 0.f};
#pragma unroll
      for (int i = 0; i < 16; ++i) sv += qr[i] * krow[i];
      float s = sv.x + sv.y + sv.z + sv.w;
      const int kg = k0 + kk;
      if (useb && kg >= 1) s += bcol[(size_t)(kg - 1) * PP];

      const f32x4* vrow = (const f32x4*)Vs[kk];
      if (s <= m) {
        const float p = expf(s - m);
        l += p;
#pragma unroll
        for (int i = 0; i < 16; ++i) acc[i] += p * vrow[i];
      } else {
        const float corr = expf(m - s);
        l = l * corr + 1.f;
#pragma unroll
        for (int i = 0; i < 16; ++i) acc[i] = acc[i] * corr + vrow[i];
        m = s;
      }
    }
  }

  if (valid) {
    const float inv = 1.f / l;
    f32x4* o4 = (f32x4*)(o + ((size_t)(b * NTOK + n) * DD) + h * DHH);
#pragma unroll
    for (int i = 0; i < 16; ++i) o4[i] = acc[i] * inv;
  }
}

// ---------------------------------------------------------------------------
extern "C" void kernel_launch(void* const* d_in, const int* in_sizes, int n_in,
                              void* d_out, int out_size, void* d_ws, size_t ws_size,
                              hipStream_t stream) {
  const float* x            = (const float*)d_in[0];
  const float* logit_w      = (const float*)d_in[1];
  const float* q_w          = (const float*)d_in[2];
  const float* kv_w         = (const float*)d_in[3];
  const float* out_w        = (const float*)d_in[4];
  const float* out_b        = (const float*)d_in[5];
  const float* cpb_w1       = (const float*)d_in[6];
  const float* cpb_b1       = (const float*)d_in[7];
  const float* cpb_w2       = (const float*)d_in[8];
  const float* cpb_b2       = (const float*)d_in[9];
  const float* u_pos        = (const float*)d_in[10];
  const float* P_pos        = (const float*)d_in[11];
  const float* tile_centers = (const float*)d_in[12];
  float* out = (float*)d_out;

  float* ws    = (float*)d_ws;
  float* ctx   = ws;
  float* qbuf  = ctx   + (size_t)BB * KTOK * DD;
  float* kvbuf = qbuf  + (size_t)BB * NTOK * DD;
  float* biasT = kvbuf + (size_t)BB * KTOK * 2 * DD;
  float* obuf  = biasT + (size_t)HH * KCC * PP;

  const int Mq = BB * NTOK;   // 16400
  const int Mkv = BB * KTOK;  // 4112

  ctx_kernel<<<BB * TT, 256, 0, stream>>>(x, logit_w, ctx);
  gemm_nt_f16split_kernel<<<dim3(DD / 128, (Mq + 127) / 128), 256, 0, stream>>>(
      x, q_w, nullptr, qbuf, Mq, DD);
  gemm_nt_f16split_kernel<<<dim3(2 * DD / 128, (Mkv + 127) / 128), 256, 0, stream>>>(
      ctx, kv_w, nullptr, kvbuf, Mkv, 2 * DD);
  cpb_kernel<<<(PP * KCC) / 256, 256, 0, stream>>>(
      P_pos, tile_centers, u_pos, cpb_w1, cpb_b1, cpb_w2, cpb_b2, biasT);
  attn_kernel<<<dim3((NTOK + 255) / 256, HH, BB), 256, 0, stream>>>(
      qbuf, kvbuf, biasT, obuf);
  gemm_nt_f16split_kernel<<<dim3(DD / 128, (Mq + 127) / 128), 256, 0, stream>>>(
      obuf, out_w, out_b, out, Mq, DD);
}

// Round 3
// 513.856 us; speedup vs baseline: 3.8898x; 1.6270x over previous
//
#include <hip/hip_runtime.h>
#include <math.h>

namespace {
constexpr int BB   = 16;    // batch
constexpr int SS   = 32;    // grid side
constexpr int TT   = 256;   // tiles
constexpr int PP   = 1024;  // patches
constexpr int NTOK = 1025;  // N = R + P
constexpr int KCC  = 256;   // KC
constexpr int KTOK = 257;   // K = R + KC
constexpr int DD   = 768;
constexpr int HH   = 12;
constexpr int DHH  = 64;
}

typedef _Float16 f16x8 __attribute__((ext_vector_type(8)));
typedef _Float16 f16x4 __attribute__((ext_vector_type(4)));
typedef float f32x4 __attribute__((ext_vector_type(4)));

// ---------------------------------------------------------------------------
// 1. tile-context pooling
// ---------------------------------------------------------------------------
__global__ __launch_bounds__(256) void ctx_kernel(
    const float* __restrict__ x, const float* __restrict__ logit_w,
    float* __restrict__ ctx) {
  const int blk = blockIdx.x;
  const int b = blk >> 8;
  const int t = blk & 255;
  const int tid = threadIdx.x;
  const float* xb = x + (size_t)b * NTOK * DD;

  int prow[4];
#pragma unroll
  for (int s = 0; s < 4; ++s)
    prow[s] = 1 + ((t >> 4) * 2 + (s >> 1)) * SS + ((t & 15) * 2 + (s & 1));

  float part[4] = {0.f, 0.f, 0.f, 0.f};
  for (int d = tid; d < DD; d += 256) {
    const float lw = logit_w[d];
#pragma unroll
    for (int s = 0; s < 4; ++s) part[s] += xb[(size_t)prow[s] * DD + d] * lw;
  }

  __shared__ float red[256];
  float score[4];
#pragma unroll
  for (int s = 0; s < 4; ++s) {
    red[tid] = part[s];
    __syncthreads();
    for (int off = 128; off > 0; off >>= 1) {
      if (tid < off) red[tid] += red[tid + off];
      __syncthreads();
    }
    score[s] = red[0];
    __syncthreads();
  }

  const float mx = fmaxf(fmaxf(score[0], score[1]), fmaxf(score[2], score[3]));
  float e[4], sum = 0.f;
#pragma unroll
  for (int s = 0; s < 4; ++s) { e[s] = expf(score[s] - mx); sum += e[s]; }
  const float inv = 1.f / sum;

  float* crow = ctx + ((size_t)b * KTOK + 1 + t) * DD;
  for (int d = tid; d < DD; d += 256) {
    float acc = 0.f;
#pragma unroll
    for (int s = 0; s < 4; ++s) acc += (e[s] * inv) * xb[(size_t)prow[s] * DD + d];
    crow[d] = acc;
  }
  if (t == 0) {
    float* dst = ctx + (size_t)b * KTOK * DD;
    for (int d = tid; d < DD; d += 256) dst[d] = xb[d];
  }
}

// ---------------------------------------------------------------------------
// 2. fp16-split MFMA NT GEMM (unchanged from round 2; passed at 2.4e-4)
// ---------------------------------------------------------------------------
__global__ __launch_bounds__(256) void gemm_nt_f16split_kernel(
    const float* __restrict__ A, const float* __restrict__ W,
    const float* __restrict__ bias, float* __restrict__ C,
    int M, int Nout) {
  constexpr int BK = 32;
  constexpr int LDT = BK + 8;
  alignas(16) __shared__ _Float16 Ah[128][LDT];
  alignas(16) __shared__ _Float16 Al[128][LDT];
  alignas(16) __shared__ _Float16 Wh[128][LDT];
  alignas(16) __shared__ _Float16 Wl[128][LDT];

  const int tid = threadIdx.x;
  const int lane = tid & 63;
  const int wid = tid >> 6;
  const int awm = (wid >> 1) * 64;
  const int awn = (wid & 1) * 64;
  const int fr = lane & 15;
  const int kb = (lane >> 4) * 8;

  const int row0 = blockIdx.y * 128;
  const int col0 = blockIdx.x * 128;

  const int sr = tid >> 3;
  const int sc = (tid & 7) * 4;

  const f32x4 zero = {0.f, 0.f, 0.f, 0.f};
  f32x4 acc[4][4];
#pragma unroll
  for (int i = 0; i < 4; ++i)
#pragma unroll
    for (int j = 0; j < 4; ++j) acc[i][j] = zero;

  for (int k0 = 0; k0 < DD; k0 += BK) {
    __syncthreads();
#pragma unroll
    for (int rr = 0; rr < 4; ++rr) {
      const int m = sr + 32 * rr;
      const int gr = row0 + m;
      float4 v = make_float4(0.f, 0.f, 0.f, 0.f);
      if (gr < M) v = *(const float4*)&A[(size_t)gr * DD + k0 + sc];
      float va[4] = {v.x, v.y, v.z, v.w};
#pragma unroll
      for (int e = 0; e < 4; ++e) {
        const _Float16 hi = (_Float16)va[e];
        Ah[m][sc + e] = hi;
        Al[m][sc + e] = (_Float16)(va[e] - (float)hi);
      }
      const float4 wv = *(const float4*)&W[(size_t)(col0 + m) * DD + k0 + sc];
      float wa[4] = {wv.x, wv.y, wv.z, wv.w};
#pragma unroll
      for (int e = 0; e < 4; ++e) {
        const _Float16 hi = (_Float16)wa[e];
        Wh[m][sc + e] = hi;
        Wl[m][sc + e] = (_Float16)(wa[e] - (float)hi);
      }
    }
    __syncthreads();

    f16x8 ah[4], al[4], bh[4], bl[4];
#pragma unroll
    for (int i = 0; i < 4; ++i) {
      ah[i] = *(const f16x8*)&Ah[awm + i * 16 + fr][kb];
      al[i] = *(const f16x8*)&Al[awm + i * 16 + fr][kb];
      bh[i] = *(const f16x8*)&Wh[awn + i * 16 + fr][kb];
      bl[i] = *(const f16x8*)&Wl[awn + i * 16 + fr][kb];
    }
#pragma unroll
    for (int i = 0; i < 4; ++i)
#pragma unroll
      for (int j = 0; j < 4; ++j) {
        acc[i][j] = __builtin_amdgcn_mfma_f32_16x16x32_f16(ah[i], bh[j], acc[i][j], 0, 0, 0);
        acc[i][j] = __builtin_amdgcn_mfma_f32_16x16x32_f16(ah[i], bl[j], acc[i][j], 0, 0, 0);
        acc[i][j] = __builtin_amdgcn_mfma_f32_16x16x32_f16(al[i], bh[j], acc[i][j], 0, 0, 0);
      }
  }

#pragma unroll
  for (int i = 0; i < 4; ++i) {
    const int rbase = row0 + awm + i * 16 + ((lane >> 4) << 2);
#pragma unroll
    for (int reg = 0; reg < 4; ++reg) {
      const int gr = rbase + reg;
      if (gr >= M) continue;
      float* crow = C + (size_t)gr * Nout + col0;
#pragma unroll
      for (int j = 0; j < 4; ++j) {
        const int gc = awn + j * 16 + fr;
        float v = acc[i][j][reg];
        if (bias) v += bias[col0 + gc];
        crow[gc] = v;
      }
    }
  }
}

// ---------------------------------------------------------------------------
// 3. CPB bias MLP -> bias[h][p][kc]  (layout changed: contiguous in kc so a
//    16-lane MFMA fragment group reads one 64B line)
// ---------------------------------------------------------------------------
__global__ __launch_bounds__(256) void cpb_kernel(
    const float* __restrict__ P_pos, const float* __restrict__ tile_centers,
    const float* __restrict__ u_pos,
    const float* __restrict__ w1, const float* __restrict__ b1,
    const float* __restrict__ w2, const float* __restrict__ b2,
    float* __restrict__ biasT) {
  const int idx = blockIdx.x * 256 + threadIdx.x;
  const int c = idx >> 10;
  const int p = idx & 1023;

  const float px = P_pos[p * 3 + 0], py = P_pos[p * 3 + 1], pz = P_pos[p * 3 + 2];
  const float kx = tile_centers[c * 3 + 0] + u_pos[0];
  const float ky = tile_centers[c * 3 + 1] + u_pos[1];
  const float kz = tile_centers[c * 3 + 2] + u_pos[2];
  const float dx = px - kx, dy = py - ky, dz = pz - kz;
  const float fx = copysignf(log1pf(fabsf(dx)), dx);
  const float fy = copysignf(log1pf(fabsf(dy)), dy);
  const float fz = -dz;

  float outh[HH];
#pragma unroll
  for (int h = 0; h < HH; ++h) outh[h] = b2[h];
  for (int j = 0; j < 32; ++j) {
    float hj = fx * w1[j * 3 + 0] + fy * w1[j * 3 + 1] + fz * w1[j * 3 + 2] + b1[j];
    hj = 0.5f * hj * (1.f + erff(hj * 0.70710678118654752f));
#pragma unroll
    for (int h = 0; h < HH; ++h) outh[h] += hj * w2[h * 32 + j];
  }
#pragma unroll
  for (int h = 0; h < HH; ++h) biasT[((size_t)h * PP + p) * KCC + c] = outh[h];
}

// ---------------------------------------------------------------------------
// 4. MFMA flash attention. Block = 256 thr = 4 waves; 64 queries/block
//    (16 per wave), K/V tiles of 64 keys in LDS (f16). Grid (17, 12, 16).
//    S frag (C layout): col=key=lane&15, row=query=(lane>>4)*4+reg.
//    P routed through per-wave LDS tile to re-enter MFMA as the A operand.
// ---------------------------------------------------------------------------
__global__ __launch_bounds__(256) void attn_mfma_kernel(
    const float* __restrict__ q, const float* __restrict__ kv,
    const float* __restrict__ biasT, float* __restrict__ o) {
  constexpr int LDT = 72;  // halves; 144B row stride -> uniform b128 banks
  alignas(16) __shared__ _Float16 Qh[64][LDT];
  alignas(16) __shared__ _Float16 Kh[64][LDT];
  alignas(16) __shared__ _Float16 Vt[64][LDT];   // [dh][key]
  alignas(16) __shared__ _Float16 Pl[4][16][LDT];

  const int tid = threadIdx.x;
  const int lane = tid & 63;
  const int w = tid >> 6;
  const int fr = lane & 15;
  const int g = lane >> 4;
  const int q0 = blockIdx.x * 64;
  const int h = blockIdx.y;
  const int b = blockIdx.z;

  const int sq = tid >> 2;        // staged token row 0..63
  const int sd = (tid & 3) * 16;  // dh offset, 16 per thread

  // ---- stage Q (once), scale folded ----
  {
    const int n = q0 + sq;
    const float* src = q + ((size_t)b * NTOK + n) * DD + h * DHH + sd;
#pragma unroll
    for (int e4 = 0; e4 < 4; ++e4) {
      float4 v = (n < NTOK) ? *(const float4*)(src + 4 * e4)
                            : make_float4(0.f, 0.f, 0.f, 0.f);
      f16x4 pk;
      pk[0] = (_Float16)(v.x * 0.125f);
      pk[1] = (_Float16)(v.y * 0.125f);
      pk[2] = (_Float16)(v.z * 0.125f);
      pk[3] = (_Float16)(v.w * 0.125f);
      *(f16x4*)&Qh[sq][sd + 4 * e4] = pk;
    }
  }
  __syncthreads();

  f16x8 qa[2];
#pragma unroll
  for (int ks = 0; ks < 2; ++ks)
    qa[ks] = *(const f16x8*)&Qh[w * 16 + fr][ks * 32 + g * 8];

  float mr_[4], lr_[4];
#pragma unroll
  for (int r = 0; r < 4; ++r) { mr_[r] = -3.0e38f; lr_[r] = 0.f; }
  f32x4 outacc[4];
#pragma unroll
  for (int j = 0; j < 4; ++j) outacc[j] = (f32x4){0.f, 0.f, 0.f, 0.f};

  for (int kt = 0; kt < 5; ++kt) {
    const int k0 = kt * 64;
    __syncthreads();  // previous tile's PV reads done before overwrite
    {
      const int key = k0 + sq;
      const bool kv_ok = key < KTOK;
      const float* srcK = kv + ((size_t)b * KTOK + key) * (2 * DD) + h * DHH + sd;
#pragma unroll
      for (int e4 = 0; e4 < 4; ++e4) {
        float4 kvv = kv_ok ? *(const float4*)(srcK + 4 * e4)
                           : make_float4(0.f, 0.f, 0.f, 0.f);
        f16x4 pk;
        pk[0] = (_Float16)kvv.x; pk[1] = (_Float16)kvv.y;
        pk[2] = (_Float16)kvv.z; pk[3] = (_Float16)kvv.w;
        *(f16x4*)&Kh[sq][sd + 4 * e4] = pk;
        float4 vv = kv_ok ? *(const float4*)(srcK + DD + 4 * e4)
                          : make_float4(0.f, 0.f, 0.f, 0.f);
        Vt[sd + 4 * e4 + 0][sq] = (_Float16)vv.x;
        Vt[sd + 4 * e4 + 1][sq] = (_Float16)vv.y;
        Vt[sd + 4 * e4 + 2][sq] = (_Float16)vv.z;
        Vt[sd + 4 * e4 + 3][sq] = (_Float16)vv.w;
      }
    }
    __syncthreads();

    // ---- QK^T ----
    f32x4 sf[4];
#pragma unroll
    for (int f = 0; f < 4; ++f) {
      sf[f] = (f32x4){0.f, 0.f, 0.f, 0.f};
#pragma unroll
      for (int ks = 0; ks < 2; ++ks) {
        f16x8 kf = *(const f16x8*)&Kh[f * 16 + fr][ks * 32 + g * 8];
        sf[f] = __builtin_amdgcn_mfma_f32_16x16x32_f16(qa[ks], kf, sf[f], 0, 0, 0);
      }
    }

    // ---- bias + mask ----
    const int nbase = q0 + w * 16 + g * 4;
    float pm[4][4];
#pragma unroll
    for (int f = 0; f < 4; ++f) {
      const int key = k0 + f * 16 + fr;
      const bool kval = key < KTOK;
      const bool kbias = kval && (key >= 1);
      const float* bp = biasT + ((size_t)h * PP + (nbase - 1)) * KCC + (key - 1);
#pragma unroll
      for (int r = 0; r < 4; ++r) {
        const int n = nbase + r;
        float s = sf[f][r];
        if (kbias && n >= 1 && n < NTOK) s += bp[(size_t)r * KCC];
        pm[f][r] = kval ? s : -3.0e38f;
      }
    }

    // ---- online softmax (row-reduce across lane&15) ----
#pragma unroll
    for (int r = 0; r < 4; ++r) {
      float rm = fmaxf(fmaxf(pm[0][r], pm[1][r]), fmaxf(pm[2][r], pm[3][r]));
#pragma unroll
      for (int d = 1; d < 16; d <<= 1) rm = fmaxf(rm, __shfl_xor(rm, d, 64));
      const float mn = fmaxf(mr_[r], rm);
      const float corr = __expf(mr_[r] - mn);
      mr_[r] = mn;
      float rs = 0.f;
#pragma unroll
      for (int f = 0; f < 4; ++f) {
        const float p = __expf(pm[f][r] - mn);
        pm[f][r] = p;
        rs += p;
      }
#pragma unroll
      for (int d = 1; d < 16; d <<= 1) rs += __shfl_xor(rs, d, 64);
      lr_[r] = lr_[r] * corr + rs;
#pragma unroll
      for (int j = 0; j < 4; ++j) outacc[j][r] *= corr;
    }

    // ---- P: C layout -> A layout via per-wave LDS ----
#pragma unroll
    for (int f = 0; f < 4; ++f)
#pragma unroll
      for (int r = 0; r < 4; ++r)
        Pl[w][g * 4 + r][f * 16 + fr] = (_Float16)pm[f][r];

    // ---- PV ----
#pragma unroll
    for (int ks = 0; ks < 2; ++ks) {
      f16x8 pa = *(const f16x8*)&Pl[w][fr][ks * 32 + g * 8];
#pragma unroll
      for (int j = 0; j < 4; ++j) {
        f16x8 vb = *(const f16x8*)&Vt[j * 16 + fr][ks * 32 + g * 8];
        outacc[j] = __builtin_amdgcn_mfma_f32_16x16x32_f16(pa, vb, outacc[j], 0, 0, 0);
      }
    }
  }

  // ---- epilogue ----
#pragma unroll
  for (int r = 0; r < 4; ++r) {
    const int n = q0 + w * 16 + g * 4 + r;
    if (n >= NTOK) continue;
    const float inv = 1.f / lr_[r];
    float* orow = o + ((size_t)b * NTOK + n) * DD + h * DHH + fr;
#pragma unroll
    for (int j = 0; j < 4; ++j) orow[j * 16] = outacc[j][r] * inv;
  }
}

// ---------------------------------------------------------------------------
extern "C" void kernel_launch(void* const* d_in, const int* in_sizes, int n_in,
                              void* d_out, int out_size, void* d_ws, size_t ws_size,
                              hipStream_t stream) {
  const float* x            = (const float*)d_in[0];
  const float* logit_w      = (const float*)d_in[1];
  const float* q_w          = (const float*)d_in[2];
  const float* kv_w         = (const float*)d_in[3];
  const float* out_w        = (const float*)d_in[4];
  const float* out_b        = (const float*)d_in[5];
  const float* cpb_w1       = (const float*)d_in[6];
  const float* cpb_b1       = (const float*)d_in[7];
  const float* cpb_w2       = (const float*)d_in[8];
  const float* cpb_b2       = (const float*)d_in[9];
  const float* u_pos        = (const float*)d_in[10];
  const float* P_pos        = (const float*)d_in[11];
  const float* tile_centers = (const float*)d_in[12];
  float* out = (float*)d_out;

  float* ws    = (float*)d_ws;
  float* ctx   = ws;
  float* qbuf  = ctx   + (size_t)BB * KTOK * DD;
  float* kvbuf = qbuf  + (size_t)BB * NTOK * DD;
  float* biasT = kvbuf + (size_t)BB * KTOK * 2 * DD;
  float* obuf  = biasT + (size_t)HH * KCC * PP;

  const int Mq = BB * NTOK;   // 16400
  const int Mkv = BB * KTOK;  // 4112

  ctx_kernel<<<BB * TT, 256, 0, stream>>>(x, logit_w, ctx);
  gemm_nt_f16split_kernel<<<dim3(DD / 128, (Mq + 127) / 128), 256, 0, stream>>>(
      x, q_w, nullptr, qbuf, Mq, DD);
  gemm_nt_f16split_kernel<<<dim3(2 * DD / 128, (Mkv + 127) / 128), 256, 0, stream>>>(
      ctx, kv_w, nullptr, kvbuf, Mkv, 2 * DD);
  cpb_kernel<<<(PP * KCC) / 256, 256, 0, stream>>>(
      P_pos, tile_centers, u_pos, cpb_w1, cpb_b1, cpb_w2, cpb_b2, biasT);
  attn_mfma_kernel<<<dim3((NTOK + 63) / 64, HH, BB), 256, 0, stream>>>(
      qbuf, kvbuf, biasT, obuf);
  gemm_nt_f16split_kernel<<<dim3(DD / 128, (Mq + 127) / 128), 256, 0, stream>>>(
      obuf, out_w, out_b, out, Mq, DD);
}

// Round 4
// 284.982 us; speedup vs baseline: 7.0137x; 1.8031x over previous
//
#include <hip/hip_runtime.h>
#include <math.h>

namespace {
constexpr int BB   = 16;    // batch
constexpr int SS   = 32;    // grid side
constexpr int TT   = 256;   // tiles
constexpr int PP   = 1024;  // patches
constexpr int NTOK = 1025;  // N = R + P
constexpr int KCC  = 256;   // KC
constexpr int KTOK = 257;   // K = R + KC
constexpr int DD   = 768;
constexpr int HH   = 12;
constexpr int DHH  = 64;
}

typedef _Float16 f16x8 __attribute__((ext_vector_type(8)));
typedef _Float16 f16x4 __attribute__((ext_vector_type(4)));
typedef _Float16 f16x2 __attribute__((ext_vector_type(2)));
typedef float f32x4 __attribute__((ext_vector_type(4)));

#define GLOAD_LDS16(gsrc, ldst)                                               \
  __builtin_amdgcn_global_load_lds(                                           \
      (const __attribute__((address_space(1))) unsigned int*)(gsrc),          \
      (__attribute__((address_space(3))) unsigned int*)(ldst), 16, 0, 0)

// ---------------------------------------------------------------------------
// 0. fp32 -> f16 conversion (vectorized, n multiple of 8), optional scale.
// ---------------------------------------------------------------------------
__global__ __launch_bounds__(256) void cvt_f16_kernel(
    const float* __restrict__ src, _Float16* __restrict__ dst, int n, float scale) {
  const int i = (blockIdx.x * 256 + threadIdx.x) * 8;
  if (i + 8 > n) return;
  const float4 a = *(const float4*)(src + i);
  const float4 b = *(const float4*)(src + i + 4);
  f16x8 o;
  o[0] = (_Float16)(a.x * scale); o[1] = (_Float16)(a.y * scale);
  o[2] = (_Float16)(a.z * scale); o[3] = (_Float16)(a.w * scale);
  o[4] = (_Float16)(b.x * scale); o[5] = (_Float16)(b.y * scale);
  o[6] = (_Float16)(b.z * scale); o[7] = (_Float16)(b.w * scale);
  *(f16x8*)(dst + i) = o;
}

// ---------------------------------------------------------------------------
// 1. tile-context pooling -> ctxh (f16)
// ---------------------------------------------------------------------------
__global__ __launch_bounds__(256) void ctx_kernel(
    const float* __restrict__ x, const float* __restrict__ logit_w,
    _Float16* __restrict__ ctxh) {
  const int blk = blockIdx.x;
  const int b = blk >> 8;
  const int t = blk & 255;
  const int tid = threadIdx.x;
  const float* xb = x + (size_t)b * NTOK * DD;

  int prow[4];
#pragma unroll
  for (int s = 0; s < 4; ++s)
    prow[s] = 1 + ((t >> 4) * 2 + (s >> 1)) * SS + ((t & 15) * 2 + (s & 1));

  float part[4] = {0.f, 0.f, 0.f, 0.f};
  for (int d = tid; d < DD; d += 256) {
    const float lw = logit_w[d];
#pragma unroll
    for (int s = 0; s < 4; ++s) part[s] += xb[(size_t)prow[s] * DD + d] * lw;
  }

  __shared__ float red[256];
  float score[4];
#pragma unroll
  for (int s = 0; s < 4; ++s) {
    red[tid] = part[s];
    __syncthreads();
    for (int off = 128; off > 0; off >>= 1) {
      if (tid < off) red[tid] += red[tid + off];
      __syncthreads();
    }
    score[s] = red[0];
    __syncthreads();
  }

  const float mx = fmaxf(fmaxf(score[0], score[1]), fmaxf(score[2], score[3]));
  float e[4], sum = 0.f;
#pragma unroll
  for (int s = 0; s < 4; ++s) { e[s] = expf(score[s] - mx); sum += e[s]; }
  const float inv = 1.f / sum;

  _Float16* crow = ctxh + ((size_t)b * KTOK + 1 + t) * DD;
  for (int d = tid; d < DD; d += 256) {
    float acc = 0.f;
#pragma unroll
    for (int s = 0; s < 4; ++s) acc += (e[s] * inv) * xb[(size_t)prow[s] * DD + d];
    crow[d] = (_Float16)acc;
  }
  if (t == 0) {
    _Float16* dst = ctxh + (size_t)b * KTOK * DD;
    for (int d = tid; d < DD; d += 256) dst[d] = (_Float16)xb[d];
  }
}

// ---------------------------------------------------------------------------
// 2. pure-f16 MFMA NT GEMM (m97 structure): C[m,n] = sum_k A[m,k]*W[n,k].
//    128x128 tile, BK=32, 4 waves 2x2 (64x64/wave), global_load_lds staging
//    into linear [128][32] f16 LDS. K fixed = 768.
//    OUTF16=1: write _Float16 C. OUTF16=0: write float C (+bias).
// ---------------------------------------------------------------------------
template <int OUTF16>
__global__ __launch_bounds__(256) void gemm_f16_kernel(
    const _Float16* __restrict__ A, const _Float16* __restrict__ W,
    const float* __restrict__ bias, void* __restrict__ Cout,
    int M, int Nout) {
  constexpr int BK = 32;
  __shared__ _Float16 As[128 * BK];
  __shared__ _Float16 Ws[128 * BK];

  const int tid = threadIdx.x;
  const int lane = tid & 63;
  const int w = tid >> 6;
  const int fr = lane & 15;
  const int g = lane >> 4;
  const int awm = (w >> 1) * 64;
  const int awn = (w & 1) * 64;
  const int row0 = blockIdx.y * 128;
  const int col0 = blockIdx.x * 128;

  // staging: lane l covers (row = chunk + l/4, k = (l&3)*8); LDS byte = 16*l.
  const int srow = lane >> 2;
  const int skcol = (lane & 3) * 8;

  f32x4 acc[4][4];
#pragma unroll
  for (int i = 0; i < 4; ++i)
#pragma unroll
    for (int j = 0; j < 4; ++j) acc[i][j] = (f32x4){0.f, 0.f, 0.f, 0.f};

  for (int k0 = 0; k0 < 768; k0 += BK) {
    __syncthreads();  // previous iteration's fragment reads done
#pragma unroll
    for (int c = 0; c < 2; ++c) {
      const int mrow = w * 32 + c * 16 + srow;
      int ga = row0 + mrow;
      ga = ga < M ? ga : M - 1;  // clamp: garbage only lands in unstored rows
      GLOAD_LDS16(A + (size_t)ga * 768 + k0 + skcol, &As[(w * 32 + c * 16) * BK]);
      GLOAD_LDS16(W + (size_t)(col0 + mrow) * 768 + k0 + skcol,
                  &Ws[(w * 32 + c * 16) * BK]);
    }
    __syncthreads();  // drains vmcnt (compiler emits waitcnt before barrier)

    f16x8 af[4], bf[4];
#pragma unroll
    for (int i = 0; i < 4; ++i)
      af[i] = *(const f16x8*)&As[(awm + i * 16 + fr) * BK + g * 8];
#pragma unroll
    for (int j = 0; j < 4; ++j)
      bf[j] = *(const f16x8*)&Ws[(awn + j * 16 + fr) * BK + g * 8];
#pragma unroll
    for (int i = 0; i < 4; ++i)
#pragma unroll
      for (int j = 0; j < 4; ++j)
        acc[i][j] = __builtin_amdgcn_mfma_f32_16x16x32_f16(af[i], bf[j], acc[i][j], 0, 0, 0);
  }

#pragma unroll
  for (int i = 0; i < 4; ++i) {
    const int rbase = row0 + awm + i * 16 + g * 4;
#pragma unroll
    for (int reg = 0; reg < 4; ++reg) {
      const int gr = rbase + reg;
      if (gr >= M) continue;
      if constexpr (OUTF16) {
        _Float16* crow = (_Float16*)Cout + (size_t)gr * Nout + col0;
#pragma unroll
        for (int j = 0; j < 4; ++j)
          crow[awn + j * 16 + fr] = (_Float16)acc[i][j][reg];
      } else {
        float* crow = (float*)Cout + (size_t)gr * Nout + col0;
#pragma unroll
        for (int j = 0; j < 4; ++j) {
          const int gc = awn + j * 16 + fr;
          crow[gc] = acc[i][j][reg] + bias[col0 + gc];
        }
      }
    }
  }
}

// ---------------------------------------------------------------------------
// 3. CPB bias MLP -> bias[h][p][kc] (f32, contiguous in kc)
// ---------------------------------------------------------------------------
__global__ __launch_bounds__(256) void cpb_kernel(
    const float* __restrict__ P_pos, const float* __restrict__ tile_centers,
    const float* __restrict__ u_pos,
    const float* __restrict__ w1, const float* __restrict__ b1,
    const float* __restrict__ w2, const float* __restrict__ b2,
    float* __restrict__ biasT) {
  const int idx = blockIdx.x * 256 + threadIdx.x;
  const int c = idx >> 10;
  const int p = idx & 1023;

  const float px = P_pos[p * 3 + 0], py = P_pos[p * 3 + 1], pz = P_pos[p * 3 + 2];
  const float kx = tile_centers[c * 3 + 0] + u_pos[0];
  const float ky = tile_centers[c * 3 + 1] + u_pos[1];
  const float kz = tile_centers[c * 3 + 2] + u_pos[2];
  const float dx = px - kx, dy = py - ky, dz = pz - kz;
  const float fx = copysignf(log1pf(fabsf(dx)), dx);
  const float fy = copysignf(log1pf(fabsf(dy)), dy);
  const float fz = -dz;

  float outh[HH];
#pragma unroll
  for (int h = 0; h < HH; ++h) outh[h] = b2[h];
  for (int j = 0; j < 32; ++j) {
    float hj = fx * w1[j * 3 + 0] + fy * w1[j * 3 + 1] + fz * w1[j * 3 + 2] + b1[j];
    hj = 0.5f * hj * (1.f + erff(hj * 0.70710678118654752f));
#pragma unroll
    for (int h = 0; h < HH; ++h) outh[h] += hj * w2[h * 32 + j];
  }
#pragma unroll
  for (int h = 0; h < HH; ++h) biasT[((size_t)h * PP + p) * KCC + c] = outh[h];
}

// ---------------------------------------------------------------------------
// 4. MFMA flash attention, f16 in (qf, kvf) / f16 out (of).
//    Block = 4 waves, 64 queries; K/V tiles of 64 keys; grid (17, 12, 16).
// ---------------------------------------------------------------------------
__global__ __launch_bounds__(256) void attn_mfma_kernel(
    const _Float16* __restrict__ qf, const _Float16* __restrict__ kvf,
    const float* __restrict__ biasT, _Float16* __restrict__ of) {
  constexpr int LDT = 72;  // halves; 144B row stride, 16B aligned
  alignas(16) __shared__ _Float16 Qh[64][LDT];
  alignas(16) __shared__ _Float16 Kh[64][LDT];
  alignas(16) __shared__ _Float16 Vt[64][LDT];  // [dh][key]
  alignas(16) __shared__ _Float16 Pl[4][16][LDT];

  const int tid = threadIdx.x;
  const int lane = tid & 63;
  const int w = tid >> 6;
  const int fr = lane & 15;
  const int g = lane >> 4;
  const int q0 = blockIdx.x * 64;
  const int h = blockIdx.y;
  const int b = blockIdx.z;

  const int sr = tid >> 2;         // staged row 0..63
  const int sc = (tid & 3) * 16;   // halves offset within 64

  // ---- stage Q (once) ----
  {
    const int n = min(q0 + sr, NTOK - 1);
    const _Float16* src = qf + ((size_t)b * NTOK + n) * DD + h * DHH + sc;
    *(f16x8*)&Qh[sr][sc] = *(const f16x8*)src;
    *(f16x8*)&Qh[sr][sc + 8] = *(const f16x8*)(src + 8);
  }
  __syncthreads();

  f16x8 qa[2];
#pragma unroll
  for (int ks = 0; ks < 2; ++ks)
    qa[ks] = *(const f16x8*)&Qh[w * 16 + fr][ks * 32 + g * 8];

  float mr_[4], lr_[4];
#pragma unroll
  for (int r = 0; r < 4; ++r) { mr_[r] = -3.0e38f; lr_[r] = 0.f; }
  f32x4 outacc[4];
#pragma unroll
  for (int j = 0; j < 4; ++j) outacc[j] = (f32x4){0.f, 0.f, 0.f, 0.f};

  // V staging decomposition (packed-pair transposed store, 4B writes)
  const int vkp = tid & 31;         // key pair
  const int vdh = (tid >> 5) * 8;   // 8 dh rows

  for (int kt = 0; kt < 5; ++kt) {
    const int k0 = kt * 64;
    __syncthreads();
    {
      // K rows: coalesced 16B copies
      const int key = min(k0 + sr, KTOK - 1);
      const _Float16* srcK = kvf + ((size_t)b * KTOK + key) * (2 * DD) + h * DHH + sc;
      *(f16x8*)&Kh[sr][sc] = *(const f16x8*)srcK;
      *(f16x8*)&Kh[sr][sc + 8] = *(const f16x8*)(srcK + 8);
      // V: read two key rows, write transposed as packed pairs
      const int kv0 = min(k0 + 2 * vkp, KTOK - 1);
      const int kv1 = min(k0 + 2 * vkp + 1, KTOK - 1);
      const _Float16* sv0 = kvf + ((size_t)b * KTOK + kv0) * (2 * DD) + DD + h * DHH + vdh;
      const _Float16* sv1 = kvf + ((size_t)b * KTOK + kv1) * (2 * DD) + DD + h * DHH + vdh;
      const f16x8 va = *(const f16x8*)sv0;
      const f16x8 vb = *(const f16x8*)sv1;
#pragma unroll
      for (int e = 0; e < 8; ++e) {
        f16x2 pr; pr[0] = va[e]; pr[1] = vb[e];
        *(f16x2*)&Vt[vdh + e][2 * vkp] = pr;
      }
    }
    __syncthreads();

    // ---- QK^T ----
    f32x4 sf[4];
#pragma unroll
    for (int f = 0; f < 4; ++f) {
      sf[f] = (f32x4){0.f, 0.f, 0.f, 0.f};
#pragma unroll
      for (int ks = 0; ks < 2; ++ks) {
        f16x8 kf = *(const f16x8*)&Kh[f * 16 + fr][ks * 32 + g * 8];
        sf[f] = __builtin_amdgcn_mfma_f32_16x16x32_f16(qa[ks], kf, sf[f], 0, 0, 0);
      }
    }

    // ---- bias + mask ----
    const int nbase = q0 + w * 16 + g * 4;
    float pm[4][4];
#pragma unroll
    for (int f = 0; f < 4; ++f) {
      const int key = k0 + f * 16 + fr;
      const bool kval = key < KTOK;
      const bool kbias = kval && (key >= 1);
      const float* bp = biasT + ((size_t)h * PP + (nbase - 1)) * KCC + (key - 1);
#pragma unroll
      for (int r = 0; r < 4; ++r) {
        const int n = nbase + r;
        float s = sf[f][r];
        if (kbias && n >= 1 && n < NTOK) s += bp[(size_t)r * KCC];
        pm[f][r] = kval ? s : -3.0e38f;
      }
    }

    // ---- online softmax (row-reduce across fr lanes) ----
#pragma unroll
    for (int r = 0; r < 4; ++r) {
      float rm = fmaxf(fmaxf(pm[0][r], pm[1][r]), fmaxf(pm[2][r], pm[3][r]));
#pragma unroll
      for (int d = 1; d < 16; d <<= 1) rm = fmaxf(rm, __shfl_xor(rm, d, 64));
      const float mn = fmaxf(mr_[r], rm);
      const float corr = __expf(mr_[r] - mn);
      mr_[r] = mn;
      float rs = 0.f;
#pragma unroll
      for (int f = 0; f < 4; ++f) {
        const float p = __expf(pm[f][r] - mn);
        pm[f][r] = p;
        rs += p;
      }
#pragma unroll
      for (int d = 1; d < 16; d <<= 1) rs += __shfl_xor(rs, d, 64);
      lr_[r] = lr_[r] * corr + rs;
#pragma unroll
      for (int j = 0; j < 4; ++j) outacc[j][r] *= corr;
    }

    // ---- P: C layout -> A layout via per-wave LDS ----
#pragma unroll
    for (int f = 0; f < 4; ++f)
#pragma unroll
      for (int r = 0; r < 4; ++r)
        Pl[w][g * 4 + r][f * 16 + fr] = (_Float16)pm[f][r];

    // ---- PV ----
#pragma unroll
    for (int ks = 0; ks < 2; ++ks) {
      f16x8 pa = *(const f16x8*)&Pl[w][fr][ks * 32 + g * 8];
#pragma unroll
      for (int j = 0; j < 4; ++j) {
        f16x8 vb = *(const f16x8*)&Vt[j * 16 + fr][ks * 32 + g * 8];
        outacc[j] = __builtin_amdgcn_mfma_f32_16x16x32_f16(pa, vb, outacc[j], 0, 0, 0);
      }
    }
  }

  // ---- epilogue (f16 out) ----
#pragma unroll
  for (int r = 0; r < 4; ++r) {
    const int n = q0 + w * 16 + g * 4 + r;
    if (n >= NTOK) continue;
    const float inv = 1.f / lr_[r];
    _Float16* orow = of + ((size_t)b * NTOK + n) * DD + h * DHH + fr;
#pragma unroll
    for (int j = 0; j < 4; ++j) orow[j * 16] = (_Float16)(outacc[j][r] * inv);
  }
}

// ---------------------------------------------------------------------------
extern "C" void kernel_launch(void* const* d_in, const int* in_sizes, int n_in,
                              void* d_out, int out_size, void* d_ws, size_t ws_size,
                              hipStream_t stream) {
  const float* x            = (const float*)d_in[0];
  const float* logit_w      = (const float*)d_in[1];
  const float* q_w          = (const float*)d_in[2];
  const float* kv_w         = (const float*)d_in[3];
  const float* out_w        = (const float*)d_in[4];
  const float* out_b        = (const float*)d_in[5];
  const float* cpb_w1       = (const float*)d_in[6];
  const float* cpb_b1       = (const float*)d_in[7];
  const float* cpb_w2       = (const float*)d_in[8];
  const float* cpb_b2       = (const float*)d_in[9];
  const float* u_pos        = (const float*)d_in[10];
  const float* P_pos        = (const float*)d_in[11];
  const float* tile_centers = (const float*)d_in[12];
  float* out = (float*)d_out;

  const int Mq  = BB * NTOK;   // 16400
  const int Mkv = BB * KTOK;   // 4112

  char* p = (char*)d_ws;
  auto alloc = [&](size_t bytes) {
    char* r = p;
    p += (bytes + 255) & ~(size_t)255;
    return r;
  };
  _Float16* xh    = (_Float16*)alloc((size_t)Mq * DD * 2);
  _Float16* ctxh  = (_Float16*)alloc((size_t)Mkv * DD * 2);
  _Float16* qwh   = (_Float16*)alloc((size_t)DD * DD * 2);
  _Float16* kvwh  = (_Float16*)alloc((size_t)2 * DD * DD * 2);
  _Float16* owh   = (_Float16*)alloc((size_t)DD * DD * 2);
  _Float16* qbuf  = (_Float16*)alloc((size_t)Mq * DD * 2);
  _Float16* kvbuf = (_Float16*)alloc((size_t)Mkv * 2 * DD * 2);
  float*    biasT = (float*)alloc((size_t)HH * KCC * PP * 4);
  _Float16* obuf  = (_Float16*)alloc((size_t)Mq * DD * 2);

  const int n_x  = Mq * DD;        // 12,595,200
  const int n_qw = DD * DD;        // 589,824
  const int n_kw = 2 * DD * DD;    // 1,179,648

  cvt_f16_kernel<<<(n_x / 8 + 255) / 256, 256, 0, stream>>>(x, xh, n_x, 1.0f);
  cvt_f16_kernel<<<(n_qw / 8 + 255) / 256, 256, 0, stream>>>(q_w, qwh, n_qw, 0.125f);
  cvt_f16_kernel<<<(n_kw / 8 + 255) / 256, 256, 0, stream>>>(kv_w, kvwh, n_kw, 1.0f);
  cvt_f16_kernel<<<(n_qw / 8 + 255) / 256, 256, 0, stream>>>(out_w, owh, n_qw, 1.0f);

  ctx_kernel<<<BB * TT, 256, 0, stream>>>(x, logit_w, ctxh);

  gemm_f16_kernel<1><<<dim3(DD / 128, (Mq + 127) / 128), 256, 0, stream>>>(
      xh, qwh, nullptr, qbuf, Mq, DD);
  gemm_f16_kernel<1><<<dim3(2 * DD / 128, (Mkv + 127) / 128), 256, 0, stream>>>(
      ctxh, kvwh, nullptr, kvbuf, Mkv, 2 * DD);

  cpb_kernel<<<(PP * KCC) / 256, 256, 0, stream>>>(
      P_pos, tile_centers, u_pos, cpb_w1, cpb_b1, cpb_w2, cpb_b2, biasT);

  attn_mfma_kernel<<<dim3((NTOK + 63) / 64, HH, BB), 256, 0, stream>>>(
      qbuf, kvbuf, biasT, obuf);

  gemm_f16_kernel<0><<<dim3(DD / 128, (Mq + 127) / 128), 256, 0, stream>>>(
      obuf, owh, out_b, out, Mq, DD);
}

// Round 5
// 230.772 us; speedup vs baseline: 8.6613x; 1.2349x over previous
//
#include <hip/hip_runtime.h>
#include <math.h>

namespace {
constexpr int BB   = 16;    // batch
constexpr int SS   = 32;    // grid side
constexpr int TT   = 256;   // tiles
constexpr int PP   = 1024;  // patches
constexpr int NTOK = 1025;  // N = R + P
constexpr int KCC  = 256;   // KC
constexpr int KTOK = 257;   // K = R + KC
constexpr int DD   = 768;
constexpr int HH   = 12;
constexpr int DHH  = 64;
constexpr int BNP  = 1040;  // bias n-dim padded (n index 0..1039; data at 1..1024)
}

typedef _Float16 f16x8 __attribute__((ext_vector_type(8)));
typedef _Float16 f16x2 __attribute__((ext_vector_type(2)));
typedef float f32x4 __attribute__((ext_vector_type(4)));

#define GLOAD_LDS16(gsrc, ldst)                                               \
  __builtin_amdgcn_global_load_lds(                                           \
      (const __attribute__((address_space(1))) unsigned int*)(gsrc),          \
      (__attribute__((address_space(3))) unsigned int*)(ldst), 16, 0, 0)

// ---------------------------------------------------------------------------
// 0. fp32 -> f16 conversion (weights only now)
// ---------------------------------------------------------------------------
__global__ __launch_bounds__(256) void cvt_f16_kernel(
    const float* __restrict__ src, _Float16* __restrict__ dst, int n, float scale) {
  const int i = (blockIdx.x * 256 + threadIdx.x) * 8;
  if (i + 8 > n) return;
  const float4 a = *(const float4*)(src + i);
  const float4 b = *(const float4*)(src + i + 4);
  f16x8 o;
  o[0] = (_Float16)(a.x * scale); o[1] = (_Float16)(a.y * scale);
  o[2] = (_Float16)(a.z * scale); o[3] = (_Float16)(a.w * scale);
  o[4] = (_Float16)(b.x * scale); o[5] = (_Float16)(b.y * scale);
  o[6] = (_Float16)(b.z * scale); o[7] = (_Float16)(b.w * scale);
  *(f16x8*)(dst + i) = o;
}

// ---------------------------------------------------------------------------
// 1. tile-context pooling -> ctxh (f16), fused x -> xh (f16) conversion
// ---------------------------------------------------------------------------
__global__ __launch_bounds__(256) void ctx_kernel(
    const float* __restrict__ x, const float* __restrict__ logit_w,
    _Float16* __restrict__ ctxh, _Float16* __restrict__ xh) {
  const int blk = blockIdx.x;
  const int b = blk >> 8;
  const int t = blk & 255;
  const int tid = threadIdx.x;
  const float* xb = x + (size_t)b * NTOK * DD;
  _Float16* xhb = xh + (size_t)b * NTOK * DD;

  int prow[4];
#pragma unroll
  for (int s = 0; s < 4; ++s)
    prow[s] = 1 + ((t >> 4) * 2 + (s >> 1)) * SS + ((t & 15) * 2 + (s & 1));

  float part[4] = {0.f, 0.f, 0.f, 0.f};
  for (int d = tid; d < DD; d += 256) {
    const float lw = logit_w[d];
#pragma unroll
    for (int s = 0; s < 4; ++s) part[s] += xb[(size_t)prow[s] * DD + d] * lw;
  }

  __shared__ float red[256];
  float score[4];
#pragma unroll
  for (int s = 0; s < 4; ++s) {
    red[tid] = part[s];
    __syncthreads();
    for (int off = 128; off > 0; off >>= 1) {
      if (tid < off) red[tid] += red[tid + off];
      __syncthreads();
    }
    score[s] = red[0];
    __syncthreads();
  }

  const float mx = fmaxf(fmaxf(score[0], score[1]), fmaxf(score[2], score[3]));
  float e[4], sum = 0.f;
#pragma unroll
  for (int s = 0; s < 4; ++s) { e[s] = expf(score[s] - mx); sum += e[s]; }
  const float inv = 1.f / sum;

  _Float16* crow = ctxh + ((size_t)b * KTOK + 1 + t) * DD;
  for (int d = tid; d < DD; d += 256) {
    float acc = 0.f;
#pragma unroll
    for (int s = 0; s < 4; ++s) {
      const float xv = xb[(size_t)prow[s] * DD + d];
      acc += (e[s] * inv) * xv;
      xhb[(size_t)prow[s] * DD + d] = (_Float16)xv;
    }
    crow[d] = (_Float16)acc;
  }
  if (t == 0) {
    _Float16* dst = ctxh + (size_t)b * KTOK * DD;
    for (int d = tid; d < DD; d += 256) {
      const float xv = xb[d];
      dst[d] = (_Float16)xv;
      xhb[d] = (_Float16)xv;
    }
  }
}

// ---------------------------------------------------------------------------
// 2. pure-f16 MFMA NT GEMM, BK=64, XOR-swizzled LDS (conflict-free ds_read).
//    LDS[row][c'] = G[row][c' ^ (row&7)]; realized by pre-swizzling the
//    per-lane GLOBAL source (gload_lds dst is linear base+16*lane).
// ---------------------------------------------------------------------------
template <int OUTF16>
__global__ __launch_bounds__(256) void gemm_f16_kernel(
    const _Float16* __restrict__ A, const _Float16* __restrict__ W,
    const float* __restrict__ bias, void* __restrict__ Cout,
    int M, int Nout) {
  constexpr int BK = 64;
  __shared__ _Float16 As[128 * BK];
  __shared__ _Float16 Ws[128 * BK];

  const int tid = threadIdx.x;
  const int lane = tid & 63;
  const int w = tid >> 6;
  const int fr = lane & 15;
  const int g = lane >> 4;
  const int awm = (w >> 1) * 64;
  const int awn = (w & 1) * 64;
  const int row0 = blockIdx.y * 128;
  const int col0 = blockIdx.x * 128;

  // staging: lane covers LDS slot (row = c*8 + lane>>3, chunk = lane&7);
  // source chunk pre-swizzled so LDS[row][c'] = G[row][c'^(row&7)].
  const int srow = lane >> 3;                       // 0..7
  const int schunk = (lane & 7) ^ (srow & 7);       // global 16B-chunk to fetch

  f32x4 acc[4][4];
#pragma unroll
  for (int i = 0; i < 4; ++i)
#pragma unroll
    for (int j = 0; j < 4; ++j) acc[i][j] = (f32x4){0.f, 0.f, 0.f, 0.f};

  for (int k0 = 0; k0 < 768; k0 += BK) {
    __syncthreads();
#pragma unroll
    for (int c = 0; c < 4; ++c) {
      const int rl = w * 32 + c * 8 + srow;
      int ga = row0 + rl;
      ga = ga < M ? ga : M - 1;  // clamp: garbage only in unstored rows
      GLOAD_LDS16(A + (size_t)ga * 768 + k0 + schunk * 8, &As[(w * 32 + c * 8) * BK]);
      GLOAD_LDS16(W + (size_t)(col0 + rl) * 768 + k0 + schunk * 8,
                  &Ws[(w * 32 + c * 8) * BK]);
    }
    __syncthreads();

#pragma unroll
    for (int ks = 0; ks < 2; ++ks) {
      f16x8 af[4], bf[4];
#pragma unroll
      for (int i = 0; i < 4; ++i) {
        const int row = awm + i * 16 + fr;
        af[i] = *(const f16x8*)&As[row * BK + (((ks * 4 + g) ^ (fr & 7)) * 8)];
      }
#pragma unroll
      for (int j = 0; j < 4; ++j) {
        const int row = awn + j * 16 + fr;
        bf[j] = *(const f16x8*)&Ws[row * BK + (((ks * 4 + g) ^ (fr & 7)) * 8)];
      }
#pragma unroll
      for (int i = 0; i < 4; ++i)
#pragma unroll
        for (int j = 0; j < 4; ++j)
          acc[i][j] = __builtin_amdgcn_mfma_f32_16x16x32_f16(af[i], bf[j], acc[i][j], 0, 0, 0);
    }
  }

#pragma unroll
  for (int i = 0; i < 4; ++i) {
    const int rbase = row0 + awm + i * 16 + g * 4;
#pragma unroll
    for (int reg = 0; reg < 4; ++reg) {
      const int gr = rbase + reg;
      if (gr >= M) continue;
      if constexpr (OUTF16) {
        _Float16* crow = (_Float16*)Cout + (size_t)gr * Nout + col0;
#pragma unroll
        for (int j = 0; j < 4; ++j)
          crow[awn + j * 16 + fr] = (_Float16)acc[i][j][reg];
      } else {
        float* crow = (float*)Cout + (size_t)gr * Nout + col0;
#pragma unroll
        for (int j = 0; j < 4; ++j) {
          const int gc = awn + j * 16 + fr;
          crow[gc] = acc[i][j][reg] + bias[col0 + gc];
        }
      }
    }
  }
}

// ---------------------------------------------------------------------------
// 3. CPB bias MLP -> biasK[h][key_c][BNP] with n = p+1 (so attn reads an
//    aligned float4 over 4 consecutive queries); n=0 and n>=1025 zeroed.
// ---------------------------------------------------------------------------
__global__ __launch_bounds__(256) void cpb_kernel(
    const float* __restrict__ P_pos, const float* __restrict__ tile_centers,
    const float* __restrict__ u_pos,
    const float* __restrict__ w1, const float* __restrict__ b1,
    const float* __restrict__ w2, const float* __restrict__ b2,
    float* __restrict__ biasK) {
  const int idx = blockIdx.x * 256 + threadIdx.x;
  const int c = idx >> 10;
  const int p = idx & 1023;

  const float px = P_pos[p * 3 + 0], py = P_pos[p * 3 + 1], pz = P_pos[p * 3 + 2];
  const float kx = tile_centers[c * 3 + 0] + u_pos[0];
  const float ky = tile_centers[c * 3 + 1] + u_pos[1];
  const float kz = tile_centers[c * 3 + 2] + u_pos[2];
  const float dx = px - kx, dy = py - ky, dz = pz - kz;
  const float fx = copysignf(log1pf(fabsf(dx)), dx);
  const float fy = copysignf(log1pf(fabsf(dy)), dy);
  const float fz = -dz;

  float outh[HH];
#pragma unroll
  for (int h = 0; h < HH; ++h) outh[h] = b2[h];
  for (int j = 0; j < 32; ++j) {
    float hj = fx * w1[j * 3 + 0] + fy * w1[j * 3 + 1] + fz * w1[j * 3 + 2] + b1[j];
    hj = 0.5f * hj * (1.f + erff(hj * 0.70710678118654752f));
#pragma unroll
    for (int h = 0; h < HH; ++h) outh[h] += hj * w2[h * 32 + j];
  }
#pragma unroll
  for (int h = 0; h < HH; ++h) {
    float* row = biasK + ((size_t)h * KCC + c) * BNP;
    row[1 + p] = outh[h];
    if (p == 0) row[0] = 0.f;
    if (p < BNP - 1 - PP) row[1 + PP + p] = 0.f;  // 1025..1039
  }
}

// ---------------------------------------------------------------------------
// 4. MFMA flash attention: 4 waves x 32 queries = 128 q/block, grid (9,12,16).
//    Q fragments straight from global; K/V tiles (64 keys) in XOR-swizzled
//    LDS [64][64] (chunk ^= row&7 -> conflict-free b128 fragment reads);
//    per-wave P tile reused across the two 16-row fragments (wave-private).
// ---------------------------------------------------------------------------
__global__ __launch_bounds__(256) void attn_mfma_kernel(
    const _Float16* __restrict__ qf, const _Float16* __restrict__ kvf,
    const float* __restrict__ biasK, _Float16* __restrict__ of) {
  __shared__ _Float16 Kh[64 * 64];
  __shared__ _Float16 Vt[64 * 64];        // [dh][key], swizzled
  __shared__ _Float16 Pl[4][16 * 64];     // per-wave, swizzled

  const int tid = threadIdx.x;
  const int lane = tid & 63;
  const int w = tid >> 6;
  const int fr = lane & 15;
  const int g = lane >> 4;
  const int q0 = blockIdx.x * 128;
  const int h = blockIdx.y;
  const int b = blockIdx.z;

  // ---- Q fragments from global (A-layout: row=fr, k=ks*32+g*8) ----
  f16x8 qa[2][2];
#pragma unroll
  for (int i = 0; i < 2; ++i) {
    const int qrow = min(q0 + w * 32 + i * 16 + fr, NTOK - 1);
    const _Float16* src = qf + ((size_t)b * NTOK + qrow) * DD + h * DHH;
#pragma unroll
    for (int ks = 0; ks < 2; ++ks)
      qa[i][ks] = *(const f16x8*)(src + ks * 32 + g * 8);
  }

  float mr_[2][4], lr_[2][4];
#pragma unroll
  for (int i = 0; i < 2; ++i)
#pragma unroll
    for (int r = 0; r < 4; ++r) { mr_[i][r] = -3.0e38f; lr_[i][r] = 0.f; }
  f32x4 outacc[2][4];
#pragma unroll
  for (int i = 0; i < 2; ++i)
#pragma unroll
    for (int j = 0; j < 4; ++j) outacc[i][j] = (f32x4){0.f, 0.f, 0.f, 0.f};

  // staging decomposition
  const int ksr = tid >> 2;           // K row 0..63
  const int kc0 = (tid & 3) * 2;      // two 16B chunks per thread
  const int vkp = tid & 31;           // V key-pair
  const int vdh = (tid >> 5) * 8;     // V 8 dh rows

  for (int kt = 0; kt < 5; ++kt) {
    const int k0 = kt * 64;
    __syncthreads();
    {
      // K rows (swizzled chunks)
      const int key = min(k0 + ksr, KTOK - 1);
      const _Float16* srcK = kvf + ((size_t)b * KTOK + key) * (2 * DD) + h * DHH;
      const int s7 = ksr & 7;
      *(f16x8*)&Kh[ksr * 64 + ((kc0 ^ s7) * 8)] = *(const f16x8*)(srcK + kc0 * 8);
      *(f16x8*)&Kh[ksr * 64 + (((kc0 + 1) ^ s7) * 8)] = *(const f16x8*)(srcK + kc0 * 8 + 8);
      // V transposed (pair-packed, swizzled chunks)
      const int kv0 = min(k0 + 2 * vkp, KTOK - 1);
      const int kv1 = min(k0 + 2 * vkp + 1, KTOK - 1);
      const f16x8 va = *(const f16x8*)(kvf + ((size_t)b * KTOK + kv0) * (2 * DD) + DD + h * DHH + vdh);
      const f16x8 vb = *(const f16x8*)(kvf + ((size_t)b * KTOK + kv1) * (2 * DD) + DD + h * DHH + vdh);
#pragma unroll
      for (int e = 0; e < 8; ++e) {
        const int d = vdh + e;
        f16x2 pr; pr[0] = va[e]; pr[1] = vb[e];
        *(f16x2*)&Vt[d * 64 + (((vkp >> 2) ^ (d & 7)) * 8) + 2 * (vkp & 3)] = pr;
      }
    }
    __syncthreads();

#pragma unroll
    for (int i = 0; i < 2; ++i) {
      // ---- QK^T ----
      f32x4 sf[4];
#pragma unroll
      for (int f = 0; f < 4; ++f) {
        sf[f] = (f32x4){0.f, 0.f, 0.f, 0.f};
#pragma unroll
        for (int ks = 0; ks < 2; ++ks) {
          const f16x8 kf = *(const f16x8*)&Kh[(f * 16 + fr) * 64 + (((ks * 4 + g) ^ (fr & 7)) * 8)];
          sf[f] = __builtin_amdgcn_mfma_f32_16x16x32_f16(qa[i][ks], kf, sf[f], 0, 0, 0);
        }
      }

      // ---- bias (one aligned float4 per f) + mask ----
      const int nb = min(q0 + w * 32 + i * 16 + g * 4, PP);
      float pm[4][4];
#pragma unroll
      for (int f = 0; f < 4; ++f) {
        const int key = k0 + f * 16 + fr;
        const int cl = min(max(key - 1, 0), KCC - 1);
        const f32x4 b4 = *(const f32x4*)&biasK[((size_t)h * KCC + cl) * BNP + nb];
        const bool kval = key < KTOK;
        const float bm = (key >= 1) ? 1.f : 0.f;
#pragma unroll
        for (int r = 0; r < 4; ++r)
          pm[f][r] = kval ? (sf[f][r] + bm * b4[r]) : -3.0e38f;
      }

      // ---- online softmax (reduce over the 16 fr lanes) ----
#pragma unroll
      for (int r = 0; r < 4; ++r) {
        float rm = fmaxf(fmaxf(pm[0][r], pm[1][r]), fmaxf(pm[2][r], pm[3][r]));
#pragma unroll
        for (int d = 1; d < 16; d <<= 1) rm = fmaxf(rm, __shfl_xor(rm, d, 64));
        const float mn = fmaxf(mr_[i][r], rm);
        const float corr = __expf(mr_[i][r] - mn);
        mr_[i][r] = mn;
        float rs = 0.f;
#pragma unroll
        for (int f = 0; f < 4; ++f) {
          const float pv = __expf(pm[f][r] - mn);
          pm[f][r] = pv;
          rs += pv;
        }
#pragma unroll
        for (int d = 1; d < 16; d <<= 1) rs += __shfl_xor(rs, d, 64);
        lr_[i][r] = lr_[i][r] * corr + rs;
#pragma unroll
        for (int j = 0; j < 4; ++j) outacc[i][j][r] *= corr;
      }

      // ---- P: C layout -> A layout via wave-private swizzled LDS ----
#pragma unroll
      for (int f = 0; f < 4; ++f)
#pragma unroll
        for (int r = 0; r < 4; ++r) {
          const int prw = g * 4 + r;
          Pl[w][prw * 64 + (((2 * f + (fr >> 3)) ^ (prw & 7)) * 8) + (fr & 7)] =
              (_Float16)pm[f][r];
        }

      // ---- PV ----
#pragma unroll
      for (int ks = 0; ks < 2; ++ks) {
        const f16x8 pa = *(const f16x8*)&Pl[w][fr * 64 + (((ks * 4 + g) ^ (fr & 7)) * 8)];
#pragma unroll
        for (int j = 0; j < 4; ++j) {
          const f16x8 vbf = *(const f16x8*)&Vt[(j * 16 + fr) * 64 + (((ks * 4 + g) ^ (fr & 7)) * 8)];
          outacc[i][j] = __builtin_amdgcn_mfma_f32_16x16x32_f16(pa, vbf, outacc[i][j], 0, 0, 0);
        }
      }
    }
  }

  // ---- epilogue (f16 out) ----
#pragma unroll
  for (int i = 0; i < 2; ++i)
#pragma unroll
    for (int r = 0; r < 4; ++r) {
      const int n = q0 + w * 32 + i * 16 + g * 4 + r;
      if (n >= NTOK) continue;
      const float inv = 1.f / lr_[i][r];
      _Float16* orow = of + ((size_t)b * NTOK + n) * DD + h * DHH + fr;
#pragma unroll
      for (int j = 0; j < 4; ++j) orow[j * 16] = (_Float16)(outacc[i][j][r] * inv);
    }
}

// ---------------------------------------------------------------------------
extern "C" void kernel_launch(void* const* d_in, const int* in_sizes, int n_in,
                              void* d_out, int out_size, void* d_ws, size_t ws_size,
                              hipStream_t stream) {
  const float* x            = (const float*)d_in[0];
  const float* logit_w      = (const float*)d_in[1];
  const float* q_w          = (const float*)d_in[2];
  const float* kv_w         = (const float*)d_in[3];
  const float* out_w        = (const float*)d_in[4];
  const float* out_b        = (const float*)d_in[5];
  const float* cpb_w1       = (const float*)d_in[6];
  const float* cpb_b1       = (const float*)d_in[7];
  const float* cpb_w2       = (const float*)d_in[8];
  const float* cpb_b2       = (const float*)d_in[9];
  const float* u_pos        = (const float*)d_in[10];
  const float* P_pos        = (const float*)d_in[11];
  const float* tile_centers = (const float*)d_in[12];
  float* out = (float*)d_out;

  const int Mq  = BB * NTOK;   // 16400
  const int Mkv = BB * KTOK;   // 4112

  char* p = (char*)d_ws;
  auto alloc = [&](size_t bytes) {
    char* r = p;
    p += (bytes + 255) & ~(size_t)255;
    return r;
  };
  _Float16* xh    = (_Float16*)alloc((size_t)Mq * DD * 2);
  _Float16* ctxh  = (_Float16*)alloc((size_t)Mkv * DD * 2);
  _Float16* qwh   = (_Float16*)alloc((size_t)DD * DD * 2);
  _Float16* kvwh  = (_Float16*)alloc((size_t)2 * DD * DD * 2);
  _Float16* owh   = (_Float16*)alloc((size_t)DD * DD * 2);
  _Float16* qbuf  = (_Float16*)alloc((size_t)Mq * DD * 2);
  _Float16* kvbuf = (_Float16*)alloc((size_t)Mkv * 2 * DD * 2);
  float*    biasK = (float*)alloc((size_t)HH * KCC * BNP * 4);
  _Float16* obuf  = (_Float16*)alloc((size_t)Mq * DD * 2);

  const int n_qw = DD * DD;        // 589,824
  const int n_kw = 2 * DD * DD;    // 1,179,648

  cvt_f16_kernel<<<(n_qw / 8 + 255) / 256, 256, 0, stream>>>(q_w, qwh, n_qw, 0.125f);
  cvt_f16_kernel<<<(n_kw / 8 + 255) / 256, 256, 0, stream>>>(kv_w, kvwh, n_kw, 1.0f);
  cvt_f16_kernel<<<(n_qw / 8 + 255) / 256, 256, 0, stream>>>(out_w, owh, n_qw, 1.0f);

  ctx_kernel<<<BB * TT, 256, 0, stream>>>(x, logit_w, ctxh, xh);

  gemm_f16_kernel<1><<<dim3(DD / 128, (Mq + 127) / 128), 256, 0, stream>>>(
      xh, qwh, nullptr, qbuf, Mq, DD);
  gemm_f16_kernel<1><<<dim3(2 * DD / 128, (Mkv + 127) / 128), 256, 0, stream>>>(
      ctxh, kvwh, nullptr, kvbuf, Mkv, 2 * DD);

  cpb_kernel<<<(PP * KCC) / 256, 256, 0, stream>>>(
      P_pos, tile_centers, u_pos, cpb_w1, cpb_b1, cpb_w2, cpb_b2, biasK);

  attn_mfma_kernel<<<dim3((NTOK + 127) / 128, HH, BB), 256, 0, stream>>>(
      qbuf, kvbuf, biasK, obuf);

  gemm_f16_kernel<0><<<dim3(DD / 128, (Mq + 127) / 128), 256, 0, stream>>>(
      obuf, owh, out_b, out, Mq, DD);
}